// Round 1
// 2276.103 us; speedup vs baseline: 1.1282x; 1.1282x over previous
//
#include <hip/hip_runtime.h>
#include <hip/hip_bf16.h>
#include <cstdint>

typedef __hip_bfloat16 bf16;
typedef __attribute__((ext_vector_type(8))) short short8;
typedef __attribute__((ext_vector_type(4))) float floatx4;

#define AS1 __attribute__((address_space(1)))
#define AS3 __attribute__((address_space(3)))

__device__ __forceinline__ int imin(int a, int b) { return a < b ? a : b; }

__device__ __forceinline__ void async_copy16(const void* g, void* l) {
  __builtin_amdgcn_global_load_lds((const AS1 uint32_t*)g, (AS3 uint32_t*)l, 16, 0, 0);
}

// ---------------------------------------------------------------------------
// W [h][in][out] fp32  ->  Wt [h][out][in] bf16   (1600x1600 per head)
// grid (25, 25, 8), block 256
__global__ __launch_bounds__(256) void transpose_w(const float* __restrict__ W,
                                                   bf16* __restrict__ Wt) {
  __shared__ float tile[64][65];
  const float* Wh = W + (size_t)blockIdx.z * 2560000;
  bf16* Wth = Wt + (size_t)blockIdx.z * 2560000;
  const int i0 = blockIdx.x * 64;  // in-dim base
  const int o0 = blockIdx.y * 64;  // out-dim base
  for (int e = threadIdx.x; e < 4096; e += 256) {
    int r = e >> 6, c = e & 63;  // r: in offset, c: out offset
    tile[r][c] = Wh[(size_t)(i0 + r) * 1600 + o0 + c];
  }
  __syncthreads();
  for (int e = threadIdx.x; e < 4096; e += 256) {
    int r = e >> 6, c = e & 63;  // r: out offset, c: in offset
    Wth[(size_t)(o0 + r) * 1600 + i0 + c] = __float2bfloat16(tile[c][r]);
  }
}

// ---------------------------------------------------------------------------
// x [N][64][256][25] fp32 -> xf [n*256+t][c*25+v] bf16
// grid (2, 32, 32): (c-block of 32, t-chunk of 8, n), block 256
__global__ __launch_bounds__(256) void pack_x(const float* __restrict__ X,
                                              bf16* __restrict__ Xf) {
  __shared__ float tile[32 * 200];  // [c_local][t_local*25+v]
  const int n = blockIdx.z, tb = blockIdx.y * 8, cb = blockIdx.x * 32;
  const float* Xn = X + (size_t)n * 64 * 6400;
  for (int e = threadIdx.x; e < 6400; e += 256) {
    int c = e / 200, rv = e % 200;  // rv = t_local*25 + v, contiguous in x
    tile[e] = Xn[(size_t)(cb + c) * 6400 + tb * 25 + rv];
  }
  __syncthreads();
  bf16* dst = Xf + ((size_t)n * 256 + tb) * 1600 + cb * 25;
  for (int e = threadIdx.x; e < 6400; e += 256) {
    int t = e / 800, j = e % 800;  // j = c_local*25 + v
    int c = j / 25, v = j % 25;
    dst[(size_t)t * 1600 + j] = __float2bfloat16(tile[c * 200 + t * 25 + v]);
  }
}

// ---------------------------------------------------------------------------
// 256x256-tile, BK=64, 8-wave (2Mx4N), phase-pipelined bf16 MFMA GEMM.
// Schedule per K-tile: 4 quadrant phases, each
//   {ds_read frags | stage next tile (other buffer) -> barrier -> lgkmcnt(0)
//    -> setprio(1) -> 16 MFMA -> setprio(0) -> barrier};
// single vmcnt(0) per K-tile at the boundary (loads issued 3-4 phases early).
// LDS: linear dest for global_load_lds; XOR granule swizzle applied on the
// per-lane GLOBAL source and on the ds_read address (both-sides involution),
// so fragment reads are bank-conflict-free.
//
// FMODE 0: K/Q proj  A=act[8192,1600]  B=Wt flat[12800,1600] +bias -> [n,h,t,d] bf16
// FMODE 1: V proj    A=Wvt flat[12800,1600] B=mf[8192,1600]  +bias -> [n,h,d,t] bf16
// FMODE 2: QK^T      per z: A=Q_z[256,1600] B=K_z[256,1600] *scale -> att fp32
// FMODE 3: PV        per z: A=P_z[256,256]  B=Vt_z[1600,256]       -> y bf16
template <int FMODE>
__global__ __launch_bounds__(512, 2) void gemm256(const short* __restrict__ Abase,
                                                  const short* __restrict__ Bbase,
                                                  const float* __restrict__ biasBase,
                                                  void* __restrict__ outBase) {
  constexpr int N = (FMODE == 0) ? 12800 : (FMODE == 1) ? 8192 : (FMODE == 2) ? 256 : 1600;
  constexpr int K = (FMODE == 3) ? 256 : 1600;
  constexpr int NT = K / 64;

  __shared__ short As[2][256 * 64];  // 64 KiB
  __shared__ short Bs[2][256 * 64];  // 64 KiB

  const int tid = (int)threadIdx.x;
  const int lane = tid & 63;
  const int wv = tid >> 6;  // 0..7
  const int wr = wv >> 2;   // m-half of block tile (0..1), wave owns 128 rows
  const int wc = wv & 3;    // n-quarter (0..3), wave owns 64 cols

  const int z = blockIdx.z;
  const short* A = Abase;
  const short* B = Bbase;
  if constexpr (FMODE == 2) { A += (size_t)z * 409600; B += (size_t)z * 409600; }
  if constexpr (FMODE == 3) { A += (size_t)z * 65536;  B += (size_t)z * 409600; }

  const int m0 = blockIdx.x * 256;
  const int n0 = blockIdx.y * 256;

  // ---- staging addressing: wave wv stages rows [wv*32, wv*32+32) of A and B,
  // 4 insts x 8 rows each; lane covers (row = +lr, 16B granule lc); source
  // granule pre-swizzled so linear LDS ends up XOR-swizzled.
  const int lr = lane >> 3;  // 0..7
  const int lc = lane & 7;   // 0..7
  const int sg8 = (lc ^ lr) * 8;  // swizzled source granule, in elements

  const short* AgI[4];
  const short* BgI[4];
#pragma unroll
  for (int i = 0; i < 4; i++) {
    const int ra = m0 + wv * 32 + i * 8 + lr;
    int rb = n0 + wv * 32 + i * 8 + lr;
    if constexpr (FMODE == 3) rb = imin(rb, N - 1);  // N=1600 not /256; epilogue guards
    AgI[i] = A + (size_t)ra * K + sg8;
    BgI[i] = B + (size_t)rb * K + sg8;
  }

  // ---- fragment read addressing ----
  const int fr = lane & 15;
  const int fq = lane >> 4;  // 0..3
  const int fr7 = fr & 7;
  int swz[2];
#pragma unroll
  for (int ks = 0; ks < 2; ks++) swz[ks] = ((ks * 4 + fq) ^ fr7) * 8;

  floatx4 acc[8][4] = {};
  short8 af[4][2];
  short8 bfrg[2][2];

#define STAGE_A(bb, k0)                                                     \
  { _Pragma("unroll") for (int i = 0; i < 4; i++)                           \
      async_copy16(AgI[i] + (k0), &As[bb][(wv * 32 + i * 8) * 64]); }
#define STAGE_B(bb, k0)                                                     \
  { _Pragma("unroll") for (int i = 0; i < 4; i++)                           \
      async_copy16(BgI[i] + (k0), &Bs[bb][(wv * 32 + i * 8) * 64]); }

#define GPHASE(MQ, NQ, LOADA, STAGEC, ENDC)                                            \
  {                                                                                    \
    if constexpr (LOADA) {                                                             \
      _Pragma("unroll") for (int mi = 0; mi < 4; mi++)                                 \
          _Pragma("unroll") for (int ks = 0; ks < 2; ks++)                             \
              af[mi][ks] = *(const short8*)&As[cur][(wr * 128 + MQ * 64 + mi * 16 + fr) * 64 + swz[ks]]; \
    }                                                                                  \
    _Pragma("unroll") for (int j = 0; j < 2; j++)                                      \
        _Pragma("unroll") for (int ks = 0; ks < 2; ks++)                               \
            bfrg[j][ks] = *(const short8*)&Bs[cur][(wc * 64 + NQ * 32 + j * 16 + fr) * 64 + swz[ks]]; \
    STAGEC                                                                             \
    __builtin_amdgcn_s_barrier();                                                      \
    asm volatile("s_waitcnt lgkmcnt(0)" ::: "memory");                                 \
    __builtin_amdgcn_sched_barrier(0);                                                 \
    __builtin_amdgcn_s_setprio(1);                                                     \
    _Pragma("unroll") for (int ks = 0; ks < 2; ks++)                                   \
        _Pragma("unroll") for (int mi = 0; mi < 4; mi++)                               \
            _Pragma("unroll") for (int j = 0; j < 2; j++)                              \
                acc[MQ * 4 + mi][NQ * 2 + j] = __builtin_amdgcn_mfma_f32_16x16x32_bf16( \
                    af[mi][ks], bfrg[j][ks], acc[MQ * 4 + mi][NQ * 2 + j], 0, 0, 0);   \
    __builtin_amdgcn_s_setprio(0);                                                     \
    ENDC                                                                               \
    __builtin_amdgcn_s_barrier();                                                      \
  }

  // prologue: stage tile 0 into buffer 0
  STAGE_A(0, 0)
  STAGE_B(0, 0)
  asm volatile("s_waitcnt vmcnt(0)" ::: "memory");
  __builtin_amdgcn_s_barrier();

  int cur = 0;
  for (int t = 0; t < NT; ++t) {
    const int kn = (t + 1) * 64;
    const bool pf = (t + 1 < NT);
    const int nxt = cur ^ 1;
    GPHASE(0, 0, true,  if (pf) STAGE_A(nxt, kn), )
    GPHASE(0, 1, false, if (pf) STAGE_B(nxt, kn), )
    GPHASE(1, 0, true,  , )
    GPHASE(1, 1, false, , asm volatile("s_waitcnt vmcnt(0)" ::: "memory");)
    cur = nxt;
  }
#undef GPHASE
#undef STAGE_A
#undef STAGE_B

  // ---- epilogue ----
  const int q4 = fq * 4;
#pragma unroll
  for (int mi = 0; mi < 8; mi++) {
    const int mmB = m0 + wr * 128 + mi * 16 + q4;
    int h1 = 0, d1 = 0;
    if constexpr (FMODE == 1) {
      const int mb = m0 + wr * 128 + mi * 16;  // 16-aligned: never crosses a head
      h1 = mb / 1600;
      d1 = mb - h1 * 1600 + q4;
    }
#pragma unroll
    for (int j = 0; j < 4; j++) {
      const int nnb = n0 + wc * 64 + j * 16;
      if constexpr (FMODE == 0) {
        const int h = nnb / 1600;  // 16-aligned: never crosses a head
        const int d = nnb - h * 1600 + fr;
        const float bv_ = biasBase[nnb + fr];
#pragma unroll
        for (int r = 0; r < 4; r++) {
          const int mmr = mmB + r;
          const int nb = mmr >> 8, tt = mmr & 255;
          ((bf16*)outBase)[(((size_t)nb * 8 + h) * 256 + tt) * 1600 + d] =
              __float2bfloat16(acc[mi][j][r] + bv_);
        }
      } else if constexpr (FMODE == 1) {
        const int nn = nnb + fr;
        const int nb = nn >> 8, tt = nn & 255;
#pragma unroll
        for (int r = 0; r < 4; r++) {
          ((bf16*)outBase)[(((size_t)nb * 8 + h1) * 1600 + (d1 + r)) * 256 + tt] =
              __float2bfloat16(acc[mi][j][r] + biasBase[mmB + r]);
        }
      } else if constexpr (FMODE == 2) {
#pragma unroll
        for (int r = 0; r < 4; r++)
          ((float*)outBase)[((size_t)z * 256 + mmB + r) * 256 + nnb + fr] =
              acc[mi][j][r] * 0.025f;  // 1/sqrt(1600)
      } else {
        if (nnb < 1600) {  // 16-aligned fragment: all-or-none
#pragma unroll
          for (int r = 0; r < 4; r++)
            ((bf16*)outBase)[((size_t)z * 256 + mmB + r) * 1600 + nnb + fr] =
                __float2bfloat16(acc[mi][j][r]);
        }
      }
    }
  }
}

// ---------------------------------------------------------------------------
// softmax over heads: att [n][h][q][k] fp32 -> P [n][h][q][k] bf16
// grid 8192, block 256; thread = one (n, q, k)
__global__ __launch_bounds__(256) void softmax_h(const float* __restrict__ att,
                                                 bf16* __restrict__ P) {
  const size_t idx = (size_t)blockIdx.x * 256 + threadIdx.x;  // 32*65536
  const int n = (int)(idx >> 16);
  const int rem = (int)(idx & 65535);
  const float* a = att + (size_t)n * 8 * 65536 + rem;
  float v[8];
  float mx = -1e30f;
#pragma unroll
  for (int h = 0; h < 8; h++) {
    v[h] = a[(size_t)h * 65536];
    mx = fmaxf(mx, v[h]);
  }
  float s = 0.f;
#pragma unroll
  for (int h = 0; h < 8; h++) {
    v[h] = __expf(v[h] - mx);
    s += v[h];
  }
  const float inv = 1.f / s;
  bf16* p = P + (size_t)n * 8 * 65536 + rem;
#pragma unroll
  for (int h = 0; h < 8; h++) p[(size_t)h * 65536] = __float2bfloat16(v[h] * inv);
}

// ---------------------------------------------------------------------------
// y [n][h][t][d=v*64+c] bf16 -> out [n][c*8+h][t][v] fp32
// grid (32 t-chunks, 8 h, 32 n), block 256
__global__ __launch_bounds__(256) void unpack_y(const bf16* __restrict__ Y,
                                                float* __restrict__ out) {
  __shared__ bf16 tile[8 * 1600];
  const int tb = blockIdx.x * 8, h = blockIdx.y, n = blockIdx.z;
  const uint32_t* src = (const uint32_t*)(Y + (((size_t)n * 8 + h) * 256 + tb) * 1600);
  uint32_t* td = (uint32_t*)tile;
  for (int e = threadIdx.x; e < 6400; e += 256) td[e] = src[e];
  __syncthreads();
  for (int r = threadIdx.x; r < 512; r += 256) {
    const int c = r >> 3, t = r & 7;
    float* o = out + (((size_t)n * 512 + c * 8 + h) * 256 + tb + t) * 25;
    const bf16* s = tile + t * 1600 + c;
#pragma unroll
    for (int v = 0; v < 25; v++) o[v] = __bfloat162float(s[v * 64]);
  }
}

// ---------------------------------------------------------------------------
extern "C" void kernel_launch(void* const* d_in, const int* in_sizes, int n_in,
                              void* d_out, int out_size, void* d_ws, size_t ws_size,
                              hipStream_t stream) {
  const float* x = (const float*)d_in[0];
  const float* m = (const float*)d_in[1];
  const float* Wk = (const float*)d_in[2];
  const float* bk = (const float*)d_in[3];
  const float* Wq = (const float*)d_in[4];
  const float* bq = (const float*)d_in[5];
  const float* Wv = (const float*)d_in[6];
  const float* bv = (const float*)d_in[7];
  float* out = (float*)d_out;

  char* ws = (char*)d_ws;
  // sizes (bytes): Wt 3*40,960,000; xf/mf 26,214,400 each; K/Q/Vt 209,715,200 each
  bf16* wkt = (bf16*)(ws);
  bf16* wqt = (bf16*)(ws + 40960000ll);
  bf16* wvt = (bf16*)(ws + 81920000ll);
  bf16* xf = (bf16*)(ws + 122880000ll);
  bf16* mf = (bf16*)(ws + 149094400ll);
  bf16* Kb = (bf16*)(ws + 175308800ll);
  bf16* Qb = (bf16*)(ws + 385024000ll);
  bf16* Vt = (bf16*)(ws + 594739200ll);
  // aliases (regions dead by the time these are written):
  float* att = (float*)(ws);            // over wkt/wqt (dead after projections)
  bf16* P = (bf16*)(ws + 67108864ll);   // over wqt tail/wvt head (dead after Vt proj)
  bf16* Yb = Qb;                        // Q dead after QK^T

  transpose_w<<<dim3(25, 25, 8), 256, 0, stream>>>(Wk, wkt);
  transpose_w<<<dim3(25, 25, 8), 256, 0, stream>>>(Wq, wqt);
  transpose_w<<<dim3(25, 25, 8), 256, 0, stream>>>(Wv, wvt);
  pack_x<<<dim3(2, 32, 32), 256, 0, stream>>>(x, xf);
  pack_x<<<dim3(2, 32, 32), 256, 0, stream>>>(m, mf);

  // head-fused projections: B/N = 8 heads x 1600 = 12800 (50 x 256, exact)
  gemm256<0><<<dim3(32, 50), 512, 0, stream>>>((const short*)xf, (const short*)wkt, bk, Kb);
  gemm256<0><<<dim3(32, 50), 512, 0, stream>>>((const short*)mf, (const short*)wqt, bq, Qb);
  gemm256<1><<<dim3(50, 32), 512, 0, stream>>>((const short*)wvt, (const short*)mf, bv, Vt);

  gemm256<2><<<dim3(1, 1, 256), 512, 0, stream>>>((const short*)Qb, (const short*)Kb, nullptr, att);
  softmax_h<<<dim3(8192), 256, 0, stream>>>(att, P);
  gemm256<3><<<dim3(1, 7, 256), 512, 0, stream>>>((const short*)P, (const short*)Vt, nullptr, Yb);

  unpack_y<<<dim3(32, 8, 32), 256, 0, stream>>>(Yb, out);
}